// Round 1
// 247.140 us; speedup vs baseline: 1.0165x; 1.0165x over previous
//
#include <hip/hip_runtime.h>

constexpr int N_DOCS = 4096;
constexpr int N_QS   = 8192;
constexpr int SPLIT  = 2;                       // blocks per row
constexpr int NBLK   = N_DOCS * SPLIT;          // 8192 blocks
constexpr int COLS4  = N_QS / 4 / SPLIT;        // 1024 fx4 (16B) elems per block
constexpr int BLOCK  = 256;
constexpr int VEC_PER_THREAD = COLS4 / BLOCK;   // 4 16B-loads per thread per array

// Native Clang vector types — __builtin_nontemporal_load requires these
// (HIP_vector_type structs are rejected).
typedef float fx4 __attribute__((ext_vector_type(4)));
typedef int   ix4 __attribute__((ext_vector_type(4)));

// Two blocks per row (SPLIT=2). Non-temporal loads retained: the harness
// re-poisons a 512 MiB region before every timed launch (the fillBuffer
// dispatches at 86-87% HBM peak in the profile); allocating reads would
// evict those dirty L3 lines into our window. nt loads don't allocate.
//
// R0->R1 experiment: 4096x64KiB blocks -> 8192x32KiB blocks. Doubles the
// number of independent read streams at the memory controllers, halves the
// tail quantum. Partials are raw (sum_t, sum_nt, cnt_t); per-row division
// moves to the final kernel (combines the two halves of each row first).
__global__ __launch_bounds__(BLOCK) void row_reduce_kernel(
    const fx4* __restrict__ cos4,
    const ix4* __restrict__ mask4,
    float4* __restrict__ part)
{
    const int blk  = blockIdx.x;
    const int row  = blk >> 1;          // SPLIT == 2
    const int half = blk & 1;
    const int tid  = threadIdx.x;
    const long base = (long)row * (N_QS / 4) + (long)half * COLS4;

    float s_t = 0.f, s_nt = 0.f, c_t = 0.f;

#pragma unroll
    for (int v = 0; v < VEC_PER_THREAD; ++v) {
        const int idx = v * BLOCK + tid;          // coalesced
        fx4 c = __builtin_nontemporal_load(&cos4[base + idx]);
        ix4 m = __builtin_nontemporal_load(&mask4[base + idx]);

        s_t  += (m.x != 0) ? (1.f - c.x) : 0.f;
        s_t  += (m.y != 0) ? (1.f - c.y) : 0.f;
        s_t  += (m.z != 0) ? (1.f - c.z) : 0.f;
        s_t  += (m.w != 0) ? (1.f - c.w) : 0.f;

        s_nt += (m.x != 0) ? 0.f : fmaxf(c.x, 0.f);
        s_nt += (m.y != 0) ? 0.f : fmaxf(c.y, 0.f);
        s_nt += (m.z != 0) ? 0.f : fmaxf(c.z, 0.f);
        s_nt += (m.w != 0) ? 0.f : fmaxf(c.w, 0.f);

        c_t  += (m.x != 0) ? 1.f : 0.f;
        c_t  += (m.y != 0) ? 1.f : 0.f;
        c_t  += (m.z != 0) ? 1.f : 0.f;
        c_t  += (m.w != 0) ? 1.f : 0.f;
    }

    // Wave-64 shuffle reduction
#pragma unroll
    for (int off = 32; off > 0; off >>= 1) {
        s_t  += __shfl_down(s_t,  off);
        s_nt += __shfl_down(s_nt, off);
        c_t  += __shfl_down(c_t,  off);
    }

    // Cross-wave reduction (4 waves)
    __shared__ float red_t[4], red_nt[4], red_c[4];
    const int wave = tid >> 6;
    const int lane = tid & 63;
    if (lane == 0) {
        red_t[wave]  = s_t;
        red_nt[wave] = s_nt;
        red_c[wave]  = c_t;
    }
    __syncthreads();

    if (tid == 0) {
        float t = 0.f, nt = 0.f, ct = 0.f;
#pragma unroll
        for (int w = 0; w < 4; ++w) { t += red_t[w]; nt += red_nt[w]; ct += red_c[w]; }
        part[blk] = make_float4(t, nt, ct, 0.f);
    }
}

// Single-block final reduction: combine the two half-row partials of each
// row, apply per-row division, then average over rows. 8192 * 16 B = 128 KiB
// of freshly-written (L2/L3-hot) reads — negligible.
__global__ __launch_bounds__(1024) void final_reduce_kernel(
    const float4* __restrict__ part,
    float* __restrict__ out)
{
    const int tid = threadIdx.x;
    float a = 0.f, b = 0.f;
#pragma unroll
    for (int r = tid; r < N_DOCS; r += 1024) {
        float4 p0 = part[2 * r];
        float4 p1 = part[2 * r + 1];
        float t  = p0.x + p1.x;
        float nt = p0.y + p1.y;
        float ct = p0.z + p1.z;
        a += t / ct;
        b += nt / ((float)N_QS - ct);
    }
#pragma unroll
    for (int off = 32; off > 0; off >>= 1) {
        a += __shfl_down(a, off);
        b += __shfl_down(b, off);
    }
    __shared__ float sa[16], sb[16];
    const int wave = tid >> 6;
    const int lane = tid & 63;
    if (lane == 0) { sa[wave] = a; sb[wave] = b; }
    __syncthreads();
    if (tid == 0) {
        float ta = 0.f, tb = 0.f;
#pragma unroll
        for (int w = 0; w < 16; ++w) { ta += sa[w]; tb += sb[w]; }
        float loss_tgt    = ta / (float)N_DOCS;
        float loss_nontgt = tb / (float)N_DOCS;
        out[0] = (loss_tgt + loss_nontgt) * 0.5f;  // loss
        out[1] = loss_tgt;                          // loss_tgt
        out[2] = loss_nontgt;                       // loss_nontgt
    }
}

extern "C" void kernel_launch(void* const* d_in, const int* in_sizes, int n_in,
                              void* d_out, int out_size, void* d_ws, size_t ws_size,
                              hipStream_t stream) {
    const fx4* cos4  = (const fx4*)d_in[0];   // cos_pred fp32 [4096,8192]
    const ix4* mask4 = (const ix4*)d_in[1];   // mask_gt  int32 [4096,8192]
    float4* part = (float4*)d_ws;             // 8192 * 16 B = 128 KiB scratch
    float*  out  = (float*)d_out;             // 3 fp32 scalars

    row_reduce_kernel<<<NBLK, BLOCK, 0, stream>>>(cos4, mask4, part);
    final_reduce_kernel<<<1, 1024, 0, stream>>>(part, out);
}